// Round 1
// baseline (19578.650 us; speedup 1.0000x reference)
//
#include <hip/hip_runtime.h>

#define TT 1024

typedef _Float16 f16;
typedef _Float16 f16x8 __attribute__((ext_vector_type(8)));
typedef float f32x4 __attribute__((ext_vector_type(4)));

__device__ __forceinline__ float sigmoidf_(float x) { return 1.0f / (1.0f + __expf(-x)); }
__device__ __forceinline__ float tanhf_(float x) { return 1.0f - 2.0f / (__expf(2.0f * x) + 1.0f); }

// Grid-wide barrier: per-WG monotonic flags, each WG's wave0 polls all 256 flags.
// Device-scope atomics + __threadfence handle cross-XCD L2 non-coherence.
__device__ __forceinline__ void grid_barrier(unsigned int* flags, int bid, int tid,
                                             unsigned int target) {
  __syncthreads();
  if (tid == 0) {
    __threadfence();  // release all prior global writes (L2 writeback)
    __hip_atomic_store(flags + bid, target, __ATOMIC_RELEASE, __HIP_MEMORY_SCOPE_AGENT);
  }
  if (tid < 64) {
    for (;;) {
      unsigned int ok = 1;
#pragma unroll
      for (int j = 0; j < 4; ++j) {
        unsigned int v = __hip_atomic_load(flags + tid + j * 64, __ATOMIC_RELAXED,
                                           __HIP_MEMORY_SCOPE_AGENT);
        ok &= (v >= target) ? 1u : 0u;
      }
      if (__all((int)ok)) break;
      __builtin_amdgcn_s_sleep(1);
    }
    __threadfence();  // acquire (L2 invalidate)
  }
  __syncthreads();
}

// One LSTM layer's persistent loop. Each WG: 8 hidden units (32 gate rows: n=gate*8+uu)
// x 64 batch rows. NCH = K/32 chunks (12 for layer0 K=384, 16 for layer1 K=512).
// Weights preconverted to fp16 B-fragments held in VGPRs for all 1024 steps.
template <int NCH, int DIN, int LAYER>
__device__ void run_layer(const float* __restrict__ x,
                          const float* __restrict__ Wih, const float* __restrict__ Whh,
                          const float* __restrict__ bias,
                          f16* __restrict__ hself, const f16* __restrict__ in2base,
                          f16* __restrict__ xbuf, unsigned int* flags,
                          float (*Gs)[33], int bid, int tid) {
  const int lane = tid & 63, wave = tid >> 6;
  const int q = lane >> 4, mm = lane & 15;
  const int lb = bid & 127;
  const int ng = lb >> 2, ms = lb & 3;
  const int b0r = ms * 64, u0 = ng * 8;

  // epilogue thread mapping: uu = tid&7 (unit), bl = tid>>3 (batch row /2 halves)
  const int uu_e = tid & 7, bl_e = tid >> 3;
  const int ucol = u0 + uu_e;
  const float bi = bias[ucol], bfv = bias[256 + ucol];
  const float bg = bias[512 + ucol], bo = bias[768 + ucol];

  // B-fragment preload (layout: B[k=(lane>>4)*8+j][n=lane&15], W row = gate*256+u0+uu)
  const int row0 = ((mm >> 3)) * 256 + u0 + (mm & 7);        // gates i,f (n-tile 0)
  const int row1 = ((mm >> 3) + 2) * 256 + u0 + (mm & 7);    // gates g,o (n-tile 1)
  f16x8 bA[NCH], bB[NCH];
#pragma unroll
  for (int c = 0; c < NCH; ++c) {
    const int k0 = c * 32 + q * 8;
    const float* s0 = (c < 8) ? (Whh + row0 * 256 + k0) : (Wih + row0 * DIN + (k0 - 256));
    const float* s1 = (c < 8) ? (Whh + row1 * 256 + k0) : (Wih + row1 * DIN + (k0 - 256));
    f16x8 v0, v1;
#pragma unroll
    for (int j = 0; j < 8; ++j) { v0[j] = (f16)s0[j]; v1[j] = (f16)s1[j]; }
    bA[c] = v0; bB[c] = v1;
  }

  float c0 = 0.f, c1 = 0.f;           // cell state, persistent in registers
  const int brow = b0r + wave * 16 + mm;

  for (int it = 0; it <= TT + 1; ++it) {
    const int i = it - 1;

    // cooperative x fp32->fp16 conversion for step i+1 (each WG = one batch row)
    if (tid < 128 && (i + 1) < TT)
      xbuf[((i + 1) & 1) * 32768 + bid * 128 + tid] =
          (f16)x[(bid * 1024 + (i + 1)) * 128 + tid];

    const bool active = (LAYER == 0) ? (i >= 0 && i < TT) : (i >= 1 && i <= TT);
    if (active) {
      const f16* hprev = hself + ((i + 1) & 1) * 65536;
      const f16* in2 = (LAYER == 0) ? (in2base + (i & 1) * 32768)
                                    : (in2base + ((i + 1) & 1) * 65536);
      f16* hout = hself + (i & 1) * 65536;

      // A fragments: A[m=lane&15][k=(lane>>4)*8+j], rows = batch
      const f16* pa1 = hprev + brow * 256 + q * 8;
      const f16* pa2 = in2 + brow * DIN + q * 8;
      f16x8 a[NCH];
#pragma unroll
      for (int c = 0; c < 8; ++c) a[c] = *(const f16x8*)(pa1 + c * 32);
#pragma unroll
      for (int c = 8; c < NCH; ++c) a[c] = *(const f16x8*)(pa2 + (c - 8) * 32);

      f32x4 acc0 = {0.f, 0.f, 0.f, 0.f}, acc1 = {0.f, 0.f, 0.f, 0.f};
#pragma unroll
      for (int c = 0; c < NCH; ++c) {
        acc0 = __builtin_amdgcn_mfma_f32_16x16x32_f16(a[c], bA[c], acc0, 0, 0, 0);
        acc1 = __builtin_amdgcn_mfma_f32_16x16x32_f16(a[c], bB[c], acc1, 0, 0, 0);
      }
      // C/D layout: col=lane&15 (gate row), row=(lane>>4)*4+reg (batch)
#pragma unroll
      for (int r = 0; r < 4; ++r) {
        Gs[wave * 16 + q * 4 + r][mm] = acc0[r];
        Gs[wave * 16 + q * 4 + r][16 + mm] = acc1[r];
      }
      __syncthreads();
      // gate nonlinearities + cell update (c in registers, 2 (b,unit) pairs/thread)
#pragma unroll
      for (int p = 0; p < 2; ++p) {
        const int b_l = bl_e + 32 * p;
        const float gi = Gs[b_l][uu_e] + bi;
        const float gf = Gs[b_l][8 + uu_e] + bfv;
        const float gg = Gs[b_l][16 + uu_e] + bg;
        const float go = Gs[b_l][24 + uu_e] + bo;
        float& cc = p ? c1 : c0;
        cc = sigmoidf_(gf) * cc + sigmoidf_(gi) * tanhf_(gg);
        const float h = sigmoidf_(go) * tanhf_(cc);
        hout[(b0r + b_l) * 256 + u0 + uu_e] = (f16)h;
      }
    }
    if (it <= TT) grid_barrier(flags, bid, tid, (unsigned)(it + 1));
  }
}

__global__ __launch_bounds__(256, 1) void lstm_persistent(
    const float* __restrict__ x,
    const float* __restrict__ Wih0, const float* __restrict__ Whh0, const float* __restrict__ b0v,
    const float* __restrict__ Wih1, const float* __restrict__ Whh1, const float* __restrict__ b1v,
    f16* h1buf, f16* h2buf, f16* xbuf, unsigned int* flags) {
  __shared__ float Gs[64][33];
  const int tid = threadIdx.x, bid = blockIdx.x;
  if (bid < 128)
    run_layer<12, 128, 0>(x, Wih0, Whh0, b0v, h1buf, (const f16*)xbuf, xbuf, flags, Gs, bid, tid);
  else
    run_layer<16, 256, 1>(x, Wih1, Whh1, b1v, h2buf, (const f16*)h1buf, xbuf, flags, Gs, bid, tid);
}

// final dense (C=10) + softmax on h2[T-1]; one wave per batch row
__global__ __launch_bounds__(64, 1) void dense_softmax_k(const f16* __restrict__ h2,
                                                         const float* __restrict__ Wd,
                                                         const float* __restrict__ bd,
                                                         float* __restrict__ out) {
  const int b = blockIdx.x, lane = threadIdx.x;
  float hv[4];
#pragma unroll
  for (int j = 0; j < 4; ++j) hv[j] = (float)h2[b * 256 + lane + 64 * j];
  float p[10];
#pragma unroll
  for (int c = 0; c < 10; ++c) {
    float s = 0.f;
#pragma unroll
    for (int j = 0; j < 4; ++j) s += hv[j] * Wd[c * 256 + lane + 64 * j];
#pragma unroll
    for (int off = 32; off >= 1; off >>= 1) s += __shfl_xor(s, off, 64);
    p[c] = s;
  }
  if (lane == 0) {
    float mx = -1e30f;
#pragma unroll
    for (int c = 0; c < 10; ++c) { p[c] += bd[c]; mx = fmaxf(mx, p[c]); }
    float den = 0.f;
#pragma unroll
    for (int c = 0; c < 10; ++c) { p[c] = __expf(p[c] - mx); den += p[c]; }
#pragma unroll
    for (int c = 0; c < 10; ++c) out[b * 10 + c] = p[c] / den;
  }
}

extern "C" void kernel_launch(void* const* d_in, const int* in_sizes, int n_in,
                              void* d_out, int out_size, void* d_ws, size_t ws_size,
                              hipStream_t stream) {
  const float* x    = (const float*)d_in[0];
  const float* Wih0 = (const float*)d_in[1];
  const float* Whh0 = (const float*)d_in[2];
  const float* b0v  = (const float*)d_in[3];
  const float* Wih1 = (const float*)d_in[4];
  const float* Whh1 = (const float*)d_in[5];
  const float* b1v  = (const float*)d_in[6];
  const float* Wd   = (const float*)d_in[7];
  const float* bd   = (const float*)d_in[8];

  char* ws = (char*)d_ws;
  // layout: h1buf[2] @0 (256KB) | h2buf[2] @256K (256KB) | xbuf[2] @512K (128KB) | flags @640K
  f16* h1buf = (f16*)(ws);
  f16* h2buf = (f16*)(ws + 256 * 1024);
  f16* xbuf  = (f16*)(ws + 512 * 1024);
  unsigned int* flags = (unsigned int*)(ws + 640 * 1024);

  // zero h1buf[1] + h2buf[0] (contiguous: initial hidden states) and flags
  hipMemsetAsync(ws + 128 * 1024, 0, 256 * 1024, stream);
  hipMemsetAsync(ws + 640 * 1024, 0, 1024, stream);

  lstm_persistent<<<256, 256, 0, stream>>>(x, Wih0, Whh0, b0v, Wih1, Whh1, b1v,
                                           h1buf, h2buf, xbuf, flags);
  // h2[T-1] lands in h2buf[0] (T even)
  dense_softmax_k<<<256, 64, 0, stream>>>(h2buf, Wd, bd, (float*)d_out);
}

// Round 2
// 13130.135 us; speedup vs baseline: 1.4911x; 1.4911x over previous
//
#include <hip/hip_runtime.h>

#define TT 1024

typedef _Float16 f16;
typedef _Float16 f16x8 __attribute__((ext_vector_type(8)));
typedef float f32x4 __attribute__((ext_vector_type(4)));

__device__ __forceinline__ float sigmoidf_(float x) { return 1.0f / (1.0f + __expf(-x)); }
__device__ __forceinline__ float tanhf_(float x) { return 1.0f - 2.0f / (__expf(2.0f * x) + 1.0f); }

// Group barrier (64 WGs per group): two-level atomicAdd arrive tree (8 leaves x 8
// members -> root), root-last WG broadcasts epoch to 4 padded release slots; each
// WG polls ONE slot with ONE lane. All flag words 256B apart (no line sharing).
// Data visibility via __threadfence release (wbl2) before arrive / acquire (inv)
// after poll — same scheme that passed round 1.
__device__ __forceinline__ void group_barrier(unsigned* leaf, unsigned* root,
                                              unsigned* relbase, int slot,
                                              unsigned e, int tid) {
  __syncthreads();  // all waves' stores complete (vmcnt0) before flush
  if (tid == 0) {
    __threadfence();  // release: push WG's writes L3-ward
    unsigned old = __hip_atomic_fetch_add(leaf, 1u, __ATOMIC_RELAXED, __HIP_MEMORY_SCOPE_AGENT);
    if ((old & 7u) == 7u) {
      unsigned o2 = __hip_atomic_fetch_add(root, 1u, __ATOMIC_RELAXED, __HIP_MEMORY_SCOPE_AGENT);
      if ((o2 & 7u) == 7u) {
#pragma unroll
        for (int s = 0; s < 4; ++s)
          __hip_atomic_store(relbase + s * 64, e, __ATOMIC_RELAXED, __HIP_MEMORY_SCOPE_AGENT);
      }
    }
    while (__hip_atomic_load(relbase + slot * 64, __ATOMIC_RELAXED,
                             __HIP_MEMORY_SCOPE_AGENT) < e)
      __builtin_amdgcn_s_sleep(2);
    __threadfence();  // acquire: invalidate stale cache before next-step reads
  }
  __syncthreads();
}

// One LSTM layer's persistent loop. Each WG: 8 hidden units (32 gate rows) x 64
// batch rows. Weights preconverted to fp16 B-fragments held in VGPRs all 1024 steps.
// LAYER 0: NCH=12 (K=256 hprev + 128 x, x read as fp32 directly, prefetched).
// LAYER 1: NCH=16 (K=256 hprev + 256 h1 from layer 0, one step behind).
template <int LAYER>
__device__ void run_layer(const float* __restrict__ xin, const f16* __restrict__ in2base,
                          const float* __restrict__ Wih, const float* __restrict__ Whh,
                          const float* __restrict__ bias, f16* __restrict__ hself,
                          unsigned* leaf, unsigned* root, unsigned* relbase, int slot,
                          float (*Gs)[33], int bid, int tid) {
  constexpr int NCH = (LAYER == 0) ? 12 : 16;
  constexpr int DIN = (LAYER == 0) ? 128 : 256;

  const int lane = tid & 63, wave = tid >> 6;
  const int q = lane >> 4, mm = lane & 15;
  const int lb = bid & 127;
  const int ng = lb >> 2, ms = lb & 3;
  const int b0r = ms * 64, u0 = ng * 8;

  const int uu_e = tid & 7, bl_e = tid >> 3;
  const int ucol = u0 + uu_e;
  const float bi = bias[ucol], bfv = bias[256 + ucol];
  const float bg = bias[512 + ucol], bo = bias[768 + ucol];

  // B-fragment preload: B[k=(lane>>4)*8+j][n=lane&15], W row = gate*256+u0+unit
  const int row0 = ((mm >> 3)) * 256 + u0 + (mm & 7);      // gates i,f
  const int row1 = ((mm >> 3) + 2) * 256 + u0 + (mm & 7);  // gates g,o
  f16x8 bA[NCH], bB[NCH];
#pragma unroll
  for (int c = 0; c < NCH; ++c) {
    const int k0 = c * 32 + q * 8;
    const float* s0 = (c < 8) ? (Whh + row0 * 256 + k0) : (Wih + row0 * DIN + (k0 - 256));
    const float* s1 = (c < 8) ? (Whh + row1 * 256 + k0) : (Wih + row1 * DIN + (k0 - 256));
    f16x8 v0, v1;
#pragma unroll
    for (int j = 0; j < 8; ++j) { v0[j] = (f16)s0[j]; v1[j] = (f16)s1[j]; }
    bA[c] = v0; bB[c] = v1;
  }

  float c0 = 0.f, c1 = 0.f;  // cell state, persistent in registers
  const int brow = b0r + wave * 16 + mm;

  f16x8 ax[4];  // layer0: prefetched x fragments (read-only input, no coherence needed)
  if (LAYER == 0) {
    const float* px = xin + (brow * 1024 + 0) * 128 + q * 8;
#pragma unroll
    for (int c = 0; c < 4; ++c) {
      float4 fa = *(const float4*)(px + c * 32);
      float4 fb = *(const float4*)(px + c * 32 + 4);
      f16x8 v; v[0]=(f16)fa.x; v[1]=(f16)fa.y; v[2]=(f16)fa.z; v[3]=(f16)fa.w;
      v[4]=(f16)fb.x; v[5]=(f16)fb.y; v[6]=(f16)fb.z; v[7]=(f16)fb.w;
      ax[c] = v;
    }
  }

  for (int it = 0; it <= TT + 1; ++it) {
    const int i = it - 1;

    const bool active = (LAYER == 0) ? (i >= 0 && i < TT) : (i >= 1 && i <= TT);
    if (active) {
      const f16* hprev = hself + ((i + 1) & 1) * 65536;
      f16* hout = hself + (i & 1) * 65536;

      // A fragments: A[m=lane&15][k=(lane>>4)*8+j], rows = batch
      const f16* pa1 = hprev + brow * 256 + q * 8;
      f16x8 a[NCH];
#pragma unroll
      for (int c = 0; c < 8; ++c) a[c] = *(const f16x8*)(pa1 + c * 32);
      if (LAYER == 0) {
#pragma unroll
        for (int c = 8; c < NCH; ++c) a[c] = ax[c - 8];
      } else {
        const f16* pa2 = in2base + ((i + 1) & 1) * 65536 + brow * 256 + q * 8;
#pragma unroll
        for (int c = 8; c < NCH; ++c) a[c] = *(const f16x8*)(pa2 + (c - 8) * 32);
      }

      f32x4 acc0 = {0.f, 0.f, 0.f, 0.f}, acc1 = {0.f, 0.f, 0.f, 0.f};
#pragma unroll
      for (int c = 0; c < NCH; ++c) {
        acc0 = __builtin_amdgcn_mfma_f32_16x16x32_f16(a[c], bA[c], acc0, 0, 0, 0);
        acc1 = __builtin_amdgcn_mfma_f32_16x16x32_f16(a[c], bB[c], acc1, 0, 0, 0);
      }
      // C/D layout: col=lane&15 (gate unit), row=(lane>>4)*4+reg (batch)
#pragma unroll
      for (int r = 0; r < 4; ++r) {
        Gs[wave * 16 + q * 4 + r][mm] = acc0[r];
        Gs[wave * 16 + q * 4 + r][16 + mm] = acc1[r];
      }
      __syncthreads();
#pragma unroll
      for (int p = 0; p < 2; ++p) {
        const int b_l = bl_e + 32 * p;
        const float gi = Gs[b_l][uu_e] + bi;
        const float gf = Gs[b_l][8 + uu_e] + bfv;
        const float gg = Gs[b_l][16 + uu_e] + bg;
        const float go = Gs[b_l][24 + uu_e] + bo;
        float& cc = p ? c1 : c0;
        cc = sigmoidf_(gf) * cc + sigmoidf_(gi) * tanhf_(gg);
        const float h = sigmoidf_(go) * tanhf_(cc);
        hout[(b0r + b_l) * 256 + u0 + uu_e] = (f16)h;
      }
    }

    // prefetch x fragments for the step computed next iteration (step index = it)
    if (LAYER == 0 && it < TT) {
      const float* px = xin + (brow * 1024 + it) * 128 + q * 8;
#pragma unroll
      for (int c = 0; c < 4; ++c) {
        float4 fa = *(const float4*)(px + c * 32);
        float4 fb = *(const float4*)(px + c * 32 + 4);
        f16x8 v; v[0]=(f16)fa.x; v[1]=(f16)fa.y; v[2]=(f16)fa.z; v[3]=(f16)fa.w;
        v[4]=(f16)fb.x; v[5]=(f16)fb.y; v[6]=(f16)fb.z; v[7]=(f16)fb.w;
        ax[c] = v;
      }
    }

    if (it <= TT) group_barrier(leaf, root, relbase, slot, (unsigned)(it + 1), tid);
  }
}

__global__ __launch_bounds__(256, 1) void lstm_persistent(
    const float* __restrict__ x,
    const float* __restrict__ Wih0, const float* __restrict__ Whh0, const float* __restrict__ b0v,
    const float* __restrict__ Wih1, const float* __restrict__ Whh1, const float* __restrict__ b1v,
    f16* h1buf, f16* h2buf, unsigned* F) {
  __shared__ float Gs[64][33];
  const int tid = threadIdx.x, bid = blockIdx.x;
  // barrier group = batch block (ms = bid&3); members: 32 layer0 + 32 layer1 WGs
  const int g = bid & 3, v = (bid >> 5) & 7, slot = (bid >> 2) & 3;
  unsigned* leaf = F + (g * 8 + v) * 64;
  unsigned* root = F + (32 + g) * 64;
  unsigned* relbase = F + (36 + g * 4) * 64;

  if (bid < 128)
    run_layer<0>(x, nullptr, Wih0, Whh0, b0v, h1buf, leaf, root, relbase, slot, Gs, bid, tid);
  else
    run_layer<1>(nullptr, h1buf, Wih1, Whh1, b1v, h2buf, leaf, root, relbase, slot, Gs, bid, tid);
}

// final dense (C=10) + softmax on h2[T-1]; one wave per batch row
__global__ __launch_bounds__(64, 1) void dense_softmax_k(const f16* __restrict__ h2,
                                                         const float* __restrict__ Wd,
                                                         const float* __restrict__ bd,
                                                         float* __restrict__ out) {
  const int b = blockIdx.x, lane = threadIdx.x;
  float hv[4];
#pragma unroll
  for (int j = 0; j < 4; ++j) hv[j] = (float)h2[b * 256 + lane + 64 * j];
  float p[10];
#pragma unroll
  for (int c = 0; c < 10; ++c) {
    float s = 0.f;
#pragma unroll
    for (int j = 0; j < 4; ++j) s += hv[j] * Wd[c * 256 + lane + 64 * j];
#pragma unroll
    for (int off = 32; off >= 1; off >>= 1) s += __shfl_xor(s, off, 64);
    p[c] = s;
  }
  if (lane == 0) {
    float mx = -1e30f;
#pragma unroll
    for (int c = 0; c < 10; ++c) { p[c] += bd[c]; mx = fmaxf(mx, p[c]); }
    float den = 0.f;
#pragma unroll
    for (int c = 0; c < 10; ++c) { p[c] = __expf(p[c] - mx); den += p[c]; }
#pragma unroll
    for (int c = 0; c < 10; ++c) out[b * 10 + c] = p[c] / den;
  }
}

extern "C" void kernel_launch(void* const* d_in, const int* in_sizes, int n_in,
                              void* d_out, int out_size, void* d_ws, size_t ws_size,
                              hipStream_t stream) {
  const float* x    = (const float*)d_in[0];
  const float* Wih0 = (const float*)d_in[1];
  const float* Whh0 = (const float*)d_in[2];
  const float* b0v  = (const float*)d_in[3];
  const float* Wih1 = (const float*)d_in[4];
  const float* Whh1 = (const float*)d_in[5];
  const float* b1v  = (const float*)d_in[6];
  const float* Wd   = (const float*)d_in[7];
  const float* bd   = (const float*)d_in[8];

  char* ws = (char*)d_ws;
  // layout: h1buf[2] @0 (256KB) | h2buf[2] @256K (256KB) | flags @512K (16KB)
  f16* h1buf = (f16*)(ws);
  f16* h2buf = (f16*)(ws + 256 * 1024);
  unsigned* F = (unsigned*)(ws + 512 * 1024);

  // zero h1buf[1] + h2buf[0] (initial hidden states, contiguous) and all flags
  hipMemsetAsync(ws + 128 * 1024, 0, 256 * 1024, stream);
  hipMemsetAsync(ws + 512 * 1024, 0, 16 * 1024, stream);

  lstm_persistent<<<256, 256, 0, stream>>>(x, Wih0, Whh0, b0v, Wih1, Whh1, b1v,
                                           h1buf, h2buf, F);
  // h2[T-1] lands in h2buf[0] (T even)
  dense_softmax_k<<<256, 64, 0, stream>>>(h2buf, Wd, bd, (float*)d_out);
}

// Round 3
// 5728.696 us; speedup vs baseline: 3.4176x; 2.2920x over previous
//
#include <hip/hip_runtime.h>

#define TT 1024

typedef _Float16 f16;
typedef _Float16 f16x8 __attribute__((ext_vector_type(8)));
typedef float f32x4 __attribute__((ext_vector_type(4)));
typedef unsigned long long u64;

__device__ __forceinline__ float sigmoidf_(float x) { return 1.0f / (1.0f + __expf(-x)); }
__device__ __forceinline__ float tanhf_(float x) { return 1.0f - 2.0f / (__expf(2.0f * x) + 1.0f); }

// Fence-free group barrier (64 WGs/group). All communicated data moves via
// agent-scope relaxed atomics (memory-side coherent, bypasses the incoherent
// per-XCD L2), so NO buffer_wbl2/buffer_inv is ever needed. __syncthreads()
// drains vmcnt(0) for every wave => all prior sc-stores are globally visible
// before the arrive. Flat 64-way counter: the last arriver's fetch_add returns
// old==63 (mod 64) and it broadcasts the epoch to 4 slots 256B apart; each WG
// polls ONE slot with ONE lane (<=16 pollers/line).
__device__ __forceinline__ void group_barrier(unsigned* cnt, unsigned* bcast, int slot,
                                              unsigned e, int tid) {
  __syncthreads();
  __atomic_signal_fence(__ATOMIC_SEQ_CST);
  if (tid == 0) {
    unsigned old = __hip_atomic_fetch_add(cnt, 1u, __ATOMIC_RELAXED, __HIP_MEMORY_SCOPE_AGENT);
    if ((old & 63u) == 63u) {
#pragma unroll
      for (int s = 0; s < 4; ++s)
        __hip_atomic_store(bcast + s * 64, e, __ATOMIC_RELAXED, __HIP_MEMORY_SCOPE_AGENT);
    }
    while (__hip_atomic_load(bcast + slot * 64, __ATOMIC_RELAXED,
                             __HIP_MEMORY_SCOPE_AGENT) < e)
      __builtin_amdgcn_s_sleep(2);
  }
  __atomic_signal_fence(__ATOMIC_SEQ_CST);
  __syncthreads();
}

__device__ __forceinline__ f16x8 load_frag_coherent(const f16* p) {
  union { u64 v[2]; f16x8 f; } u;
  u.v[0] = __hip_atomic_load((u64*)p,     __ATOMIC_RELAXED, __HIP_MEMORY_SCOPE_AGENT);
  u.v[1] = __hip_atomic_load((u64*)p + 1, __ATOMIC_RELAXED, __HIP_MEMORY_SCOPE_AGENT);
  return u.f;
}

// One LSTM layer's persistent loop. Each WG: 8 hidden units (32 gate rows) x 64
// batch rows. Weights preconverted to fp16 B-fragments held in registers all 1024
// steps. LAYER 0: NCH=12 (K=256 hprev + 128 x, x read fp32 cached, prefetched).
// LAYER 1: NCH=16 (K=256 hprev + 256 h1 from layer 0, one step behind).
template <int LAYER>
__device__ void run_layer(const float* __restrict__ xin, const f16* __restrict__ in2base,
                          const float* __restrict__ Wih, const float* __restrict__ Whh,
                          const float* __restrict__ bias, f16* __restrict__ hself,
                          unsigned* cnt, unsigned* bcast, int slot,
                          float (*Gs)[33], int bid, int tid) {
  constexpr int NCH = (LAYER == 0) ? 12 : 16;
  constexpr int DIN = (LAYER == 0) ? 128 : 256;

  const int lane = tid & 63, wave = tid >> 6;
  const int q = lane >> 4, mm = lane & 15;
  const int lb = bid & 127;
  const int ng = lb >> 2, ms = lb & 3;
  const int b0r = ms * 64, u0 = ng * 8;

  // epilogue mapping: each thread owns 1 batch row x 2 adjacent units (4B store)
  const int up_e = tid & 3, bl_e = tid >> 2;          // unit pair 0..3, batch 0..63
  const int uc0 = u0 + 2 * up_e, uc1 = uc0 + 1;
  const float bi0 = bias[uc0],       bi1 = bias[uc1];
  const float bf0 = bias[256 + uc0], bf1 = bias[256 + uc1];
  const float bg0 = bias[512 + uc0], bg1 = bias[512 + uc1];
  const float bo0 = bias[768 + uc0], bo1 = bias[768 + uc1];

  // B-fragment preload: B[k=(lane>>4)*8+j][n=lane&15], W row = gate*256+u0+unit
  const int row0 = ((mm >> 3)) * 256 + u0 + (mm & 7);      // gates i,f
  const int row1 = ((mm >> 3) + 2) * 256 + u0 + (mm & 7);  // gates g,o
  f16x8 bA[NCH], bB[NCH];
#pragma unroll
  for (int c = 0; c < NCH; ++c) {
    const int k0 = c * 32 + q * 8;
    const float* s0 = (c < 8) ? (Whh + row0 * 256 + k0) : (Wih + row0 * DIN + (k0 - 256));
    const float* s1 = (c < 8) ? (Whh + row1 * 256 + k0) : (Wih + row1 * DIN + (k0 - 256));
    f16x8 v0, v1;
#pragma unroll
    for (int j = 0; j < 8; ++j) { v0[j] = (f16)s0[j]; v1[j] = (f16)s1[j]; }
    bA[c] = v0; bB[c] = v1;
  }

  float cA = 0.f, cB = 0.f;  // cell state for the 2 owned units, registers
  const int brow = b0r + wave * 16 + mm;

  f16x8 ax[4];  // layer0: prefetched x fragments (read-only input, cached path ok)
  if (LAYER == 0) {
    const float* px = xin + (brow * 1024 + 0) * 128 + q * 8;
#pragma unroll
    for (int c = 0; c < 4; ++c) {
      float4 fa = *(const float4*)(px + c * 32);
      float4 fb = *(const float4*)(px + c * 32 + 4);
      f16x8 v; v[0]=(f16)fa.x; v[1]=(f16)fa.y; v[2]=(f16)fa.z; v[3]=(f16)fa.w;
      v[4]=(f16)fb.x; v[5]=(f16)fb.y; v[6]=(f16)fb.z; v[7]=(f16)fb.w;
      ax[c] = v;
    }
  }

  for (int it = 0; it <= TT + 1; ++it) {
    const int i = it - 1;

    const bool active = (LAYER == 0) ? (i >= 0 && i < TT) : (i >= 1 && i <= TT);
    if (active) {
      const f16* hprev = hself + ((i + 1) & 1) * 65536;
      f16* hout = hself + (i & 1) * 65536;

      // A fragments via memory-side coherent 8B atomic loads
      const f16* pa1 = hprev + brow * 256 + q * 8;
      f16x8 a[NCH];
#pragma unroll
      for (int c = 0; c < 8; ++c) a[c] = load_frag_coherent(pa1 + c * 32);
      if (LAYER == 0) {
#pragma unroll
        for (int c = 8; c < NCH; ++c) a[c] = ax[c - 8];
      } else {
        const f16* pa2 = in2base + ((i + 1) & 1) * 65536 + brow * 256 + q * 8;
#pragma unroll
        for (int c = 8; c < NCH; ++c) a[c] = load_frag_coherent(pa2 + (c - 8) * 32);
      }

      f32x4 acc0 = {0.f, 0.f, 0.f, 0.f}, acc1 = {0.f, 0.f, 0.f, 0.f};
#pragma unroll
      for (int c = 0; c < NCH; ++c) {
        acc0 = __builtin_amdgcn_mfma_f32_16x16x32_f16(a[c], bA[c], acc0, 0, 0, 0);
        acc1 = __builtin_amdgcn_mfma_f32_16x16x32_f16(a[c], bB[c], acc1, 0, 0, 0);
      }
      // C/D layout: col=lane&15 (gate unit), row=(lane>>4)*4+reg (batch)
#pragma unroll
      for (int r = 0; r < 4; ++r) {
        Gs[wave * 16 + q * 4 + r][mm] = acc0[r];
        Gs[wave * 16 + q * 4 + r][16 + mm] = acc1[r];
      }
      __syncthreads();
      {
        const float gi0 = Gs[bl_e][2 * up_e] + bi0,      gi1 = Gs[bl_e][2 * up_e + 1] + bi1;
        const float gf0 = Gs[bl_e][8 + 2 * up_e] + bf0,  gf1 = Gs[bl_e][8 + 2 * up_e + 1] + bf1;
        const float gg0 = Gs[bl_e][16 + 2 * up_e] + bg0, gg1 = Gs[bl_e][16 + 2 * up_e + 1] + bg1;
        const float go0 = Gs[bl_e][24 + 2 * up_e] + bo0, go1 = Gs[bl_e][24 + 2 * up_e + 1] + bo1;
        cA = sigmoidf_(gf0) * cA + sigmoidf_(gi0) * tanhf_(gg0);
        cB = sigmoidf_(gf1) * cB + sigmoidf_(gi1) * tanhf_(gg1);
        union { f16 h2v[2]; unsigned u; } pk;
        pk.h2v[0] = (f16)(sigmoidf_(go0) * tanhf_(cA));
        pk.h2v[1] = (f16)(sigmoidf_(go1) * tanhf_(cB));
        unsigned* dst = (unsigned*)(hout + (b0r + bl_e) * 256 + uc0);
        __hip_atomic_store(dst, pk.u, __ATOMIC_RELAXED, __HIP_MEMORY_SCOPE_AGENT);
      }
    }

    // prefetch x fragments for the step computed next iteration (step index = it)
    if (LAYER == 0 && it < TT) {
      const float* px = xin + (brow * 1024 + it) * 128 + q * 8;
#pragma unroll
      for (int c = 0; c < 4; ++c) {
        float4 fa = *(const float4*)(px + c * 32);
        float4 fb = *(const float4*)(px + c * 32 + 4);
        f16x8 v; v[0]=(f16)fa.x; v[1]=(f16)fa.y; v[2]=(f16)fa.z; v[3]=(f16)fa.w;
        v[4]=(f16)fb.x; v[5]=(f16)fb.y; v[6]=(f16)fb.z; v[7]=(f16)fb.w;
        ax[c] = v;
      }
    }

    if (it <= TT) group_barrier(cnt, bcast, slot, (unsigned)(it + 1), tid);
  }
}

__global__ __launch_bounds__(256, 1) void lstm_persistent(
    const float* __restrict__ x,
    const float* __restrict__ Wih0, const float* __restrict__ Whh0, const float* __restrict__ b0v,
    const float* __restrict__ Wih1, const float* __restrict__ Whh1, const float* __restrict__ b1v,
    f16* h1buf, f16* h2buf, unsigned* F) {
  __shared__ float Gs[64][33];
  const int tid = threadIdx.x, bid = blockIdx.x;
  // barrier group = batch block (bid&3): 32 layer0 + 32 layer1 WGs
  const int g = bid & 3, slot = (bid >> 2) & 3;
  unsigned* cnt = F + g * 1024;
  unsigned* bcast = F + g * 1024 + 256;

  if (bid < 128)
    run_layer<0>(x, nullptr, Wih0, Whh0, b0v, h1buf, cnt, bcast, slot, Gs, bid, tid);
  else
    run_layer<1>(nullptr, h1buf, Wih1, Whh1, b1v, h2buf, cnt, bcast, slot, Gs, bid, tid);
}

// final dense (C=10) + softmax on h2[T-1]; one wave per batch row
__global__ __launch_bounds__(64, 1) void dense_softmax_k(const f16* __restrict__ h2,
                                                         const float* __restrict__ Wd,
                                                         const float* __restrict__ bd,
                                                         float* __restrict__ out) {
  const int b = blockIdx.x, lane = threadIdx.x;
  float hv[4];
#pragma unroll
  for (int j = 0; j < 4; ++j) hv[j] = (float)h2[b * 256 + lane + 64 * j];
  float p[10];
#pragma unroll
  for (int c = 0; c < 10; ++c) {
    float s = 0.f;
#pragma unroll
    for (int j = 0; j < 4; ++j) s += hv[j] * Wd[c * 256 + lane + 64 * j];
#pragma unroll
    for (int off = 32; off >= 1; off >>= 1) s += __shfl_xor(s, off, 64);
    p[c] = s;
  }
  if (lane == 0) {
    float mx = -1e30f;
#pragma unroll
    for (int c = 0; c < 10; ++c) { p[c] += bd[c]; mx = fmaxf(mx, p[c]); }
    float den = 0.f;
#pragma unroll
    for (int c = 0; c < 10; ++c) { p[c] = __expf(p[c] - mx); den += p[c]; }
#pragma unroll
    for (int c = 0; c < 10; ++c) out[b * 10 + c] = p[c] / den;
  }
}

extern "C" void kernel_launch(void* const* d_in, const int* in_sizes, int n_in,
                              void* d_out, int out_size, void* d_ws, size_t ws_size,
                              hipStream_t stream) {
  const float* x    = (const float*)d_in[0];
  const float* Wih0 = (const float*)d_in[1];
  const float* Whh0 = (const float*)d_in[2];
  const float* b0v  = (const float*)d_in[3];
  const float* Wih1 = (const float*)d_in[4];
  const float* Whh1 = (const float*)d_in[5];
  const float* b1v  = (const float*)d_in[6];
  const float* Wd   = (const float*)d_in[7];
  const float* bd   = (const float*)d_in[8];

  char* ws = (char*)d_ws;
  // layout: h1buf[2] @0 (256KB) | h2buf[2] @256K (256KB) | flags @512K (16KB)
  f16* h1buf = (f16*)(ws);
  f16* h2buf = (f16*)(ws + 256 * 1024);
  unsigned* F = (unsigned*)(ws + 512 * 1024);

  // zero h1buf[1] + h2buf[0] (initial hidden states, contiguous) and all flags
  hipMemsetAsync(ws + 128 * 1024, 0, 256 * 1024, stream);
  hipMemsetAsync(ws + 512 * 1024, 0, 16 * 1024, stream);

  lstm_persistent<<<256, 256, 0, stream>>>(x, Wih0, Whh0, b0v, Wih1, Whh1, b1v,
                                           h1buf, h2buf, F);
  // h2[T-1] lands in h2buf[0] (T even)
  dense_softmax_k<<<256, 64, 0, stream>>>(h2buf, Wd, bd, (float*)d_out);
}

// Round 5
// 5571.533 us; speedup vs baseline: 3.5141x; 1.0282x over previous
//
#include <hip/hip_runtime.h>

#define TT 1024

typedef _Float16 f16;
typedef _Float16 f16x8 __attribute__((ext_vector_type(8)));
typedef float f32x4 __attribute__((ext_vector_type(4)));
typedef unsigned long long u64;

__device__ __forceinline__ float sigmoidf_(float x) { return 1.0f / (1.0f + __expf(-x)); }
__device__ __forceinline__ float tanhf_(float x) { return 1.0f - 2.0f / (__expf(2.0f * x) + 1.0f); }

// Arrival-slot group barrier (64 WGs/group), fence-free, contention-free.
// Data moves via agent-scope relaxed atomics (memory-side coherent, bypasses the
// incoherent per-XCD L2) so no cache maintenance is needed. __syncthreads()
// drains vmcnt(0) => this WG's h sc-stores are globally visible before the slot
// store. Each WG stores epoch e to its OWN 256B-padded slot (no RMW, no
// serialization); wave0 lane L polls slot L directly and __all-reduces.
__device__ __forceinline__ void group_barrier(unsigned* slots, int w, unsigned e, int tid) {
  __syncthreads();
  __atomic_signal_fence(__ATOMIC_SEQ_CST);
  if (tid == 0)
    __hip_atomic_store(slots + w * 64, e, __ATOMIC_RELAXED, __HIP_MEMORY_SCOPE_AGENT);
  if (tid < 64) {
    for (;;) {
      unsigned v = __hip_atomic_load(slots + tid * 64, __ATOMIC_RELAXED,
                                     __HIP_MEMORY_SCOPE_AGENT);
      if (__all(v >= e)) break;
      __builtin_amdgcn_s_sleep(2);
    }
  }
  __atomic_signal_fence(__ATOMIC_SEQ_CST);
  __syncthreads();
}

__device__ __forceinline__ f16x8 load_frag_coherent(const f16* p) {
  union { u64 v[2]; f16x8 f; } u;
  u.v[0] = __hip_atomic_load((u64*)p,     __ATOMIC_RELAXED, __HIP_MEMORY_SCOPE_AGENT);
  u.v[1] = __hip_atomic_load((u64*)p + 1, __ATOMIC_RELAXED, __HIP_MEMORY_SCOPE_AGENT);
  return u.f;
}

// One LSTM layer's persistent loop. Each WG: 8 hidden units (32 gate rows) x 64
// batch rows. Weights preconverted to fp16 B-fragments held in registers all 1024
// steps. LAYER 0: NCH=12 (K=256 hprev + 128 x); x is loaded raw fp32 one full
// iteration ahead (vmcnt wait lands next step -> HBM latency fully hidden) and
// converted to fp16 at first use. Chunk c covers k-elements [c*32 .. c*32+7]
// relative to q*8: two float4 at +c*32 and +c*32+4 (round-3-proven addressing).
// LAYER 1: NCH=16 (K=256 hprev + 256 h1, one step behind layer 0).
template <int LAYER>
__device__ void run_layer(const float* __restrict__ xin, const f16* __restrict__ in2base,
                          const float* __restrict__ Wih, const float* __restrict__ Whh,
                          const float* __restrict__ bias, f16* __restrict__ hself,
                          unsigned* slots, int w,
                          float (*Gs)[33], int bid, int tid) {
  constexpr int NCH = (LAYER == 0) ? 12 : 16;
  constexpr int DIN = (LAYER == 0) ? 128 : 256;

  const int lane = tid & 63, wave = tid >> 6;
  const int q = lane >> 4, mm = lane & 15;
  const int lb = bid & 127;
  const int ng = lb >> 2, ms = lb & 3;
  const int b0r = ms * 64, u0 = ng * 8;

  // epilogue mapping: each thread owns 1 batch row x 2 adjacent units (4B store)
  const int up_e = tid & 3, bl_e = tid >> 2;          // unit pair 0..3, batch 0..63
  const int uc0 = u0 + 2 * up_e, uc1 = uc0 + 1;
  const float bi0 = bias[uc0],       bi1 = bias[uc1];
  const float bf0 = bias[256 + uc0], bf1 = bias[256 + uc1];
  const float bg0 = bias[512 + uc0], bg1 = bias[512 + uc1];
  const float bo0 = bias[768 + uc0], bo1 = bias[768 + uc1];

  // B-fragment preload: B[k=(lane>>4)*8+j][n=lane&15], W row = gate*256+u0+unit
  const int row0 = ((mm >> 3)) * 256 + u0 + (mm & 7);      // gates i,f
  const int row1 = ((mm >> 3) + 2) * 256 + u0 + (mm & 7);  // gates g,o
  f16x8 bA[NCH], bB[NCH];
#pragma unroll
  for (int c = 0; c < NCH; ++c) {
    const int k0 = c * 32 + q * 8;
    const float* s0 = (c < 8) ? (Whh + row0 * 256 + k0) : (Wih + row0 * DIN + (k0 - 256));
    const float* s1 = (c < 8) ? (Whh + row1 * 256 + k0) : (Wih + row1 * DIN + (k0 - 256));
    f16x8 v0, v1;
#pragma unroll
    for (int j = 0; j < 8; ++j) { v0[j] = (f16)s0[j]; v1[j] = (f16)s1[j]; }
    bA[c] = v0; bB[c] = v1;
  }

  float cA = 0.f, cB = 0.f;  // cell state for the 2 owned units, registers
  const int brow = b0r + wave * 16 + mm;

  float4 axr[8];   // raw fp32 x for the NEXT step (loaded 1 iter ahead)
  f16x8 ax[4];     // fp16 x fragments for the CURRENT step

  for (int it = 0; it <= TT + 1; ++it) {
    const int i = it - 1;
    const bool active = (LAYER == 0) ? (i >= 0 && i < TT) : (i >= 1 && i <= TT);

    if (LAYER == 0) {
      // convert last iteration's raw x (loaded >1 step ago; vmcnt already slack)
      if (active) {
#pragma unroll
        for (int c = 0; c < 4; ++c) {
          const float4 fa = axr[2 * c], fb = axr[2 * c + 1];
          f16x8 v; v[0]=(f16)fa.x; v[1]=(f16)fa.y; v[2]=(f16)fa.z; v[3]=(f16)fa.w;
          v[4]=(f16)fb.x; v[5]=(f16)fb.y; v[6]=(f16)fb.z; v[7]=(f16)fb.w;
          ax[c] = v;
        }
      }
      // issue raw loads for step `it` (consumed next iteration)
      if (it < TT) {
        const float* px = xin + (brow * 1024 + it) * 128 + q * 8;
#pragma unroll
        for (int c = 0; c < 4; ++c) {
          axr[2 * c]     = *(const float4*)(px + c * 32);
          axr[2 * c + 1] = *(const float4*)(px + c * 32 + 4);
        }
      }
    }

    if (active) {
      const f16* hprev = hself + ((i + 1) & 1) * 65536;
      f16* hout = hself + (i & 1) * 65536;

      // A fragments via memory-side coherent 8B atomic loads
      const f16* pa1 = hprev + brow * 256 + q * 8;
      f16x8 a[NCH];
#pragma unroll
      for (int c = 0; c < 8; ++c) a[c] = load_frag_coherent(pa1 + c * 32);
      if (LAYER == 0) {
#pragma unroll
        for (int c = 8; c < NCH; ++c) a[c] = ax[c - 8];
      } else {
        const f16* pa2 = in2base + ((i + 1) & 1) * 65536 + brow * 256 + q * 8;
#pragma unroll
        for (int c = 8; c < NCH; ++c) a[c] = load_frag_coherent(pa2 + (c - 8) * 32);
      }

      f32x4 acc0 = {0.f, 0.f, 0.f, 0.f}, acc1 = {0.f, 0.f, 0.f, 0.f};
#pragma unroll
      for (int c = 0; c < NCH; ++c) {
        acc0 = __builtin_amdgcn_mfma_f32_16x16x32_f16(a[c], bA[c], acc0, 0, 0, 0);
        acc1 = __builtin_amdgcn_mfma_f32_16x16x32_f16(a[c], bB[c], acc1, 0, 0, 0);
      }
      // C/D layout: col=lane&15 (gate unit), row=(lane>>4)*4+reg (batch)
#pragma unroll
      for (int r = 0; r < 4; ++r) {
        Gs[wave * 16 + q * 4 + r][mm] = acc0[r];
        Gs[wave * 16 + q * 4 + r][16 + mm] = acc1[r];
      }
      __syncthreads();
      {
        const float gi0 = Gs[bl_e][2 * up_e] + bi0,      gi1 = Gs[bl_e][2 * up_e + 1] + bi1;
        const float gf0 = Gs[bl_e][8 + 2 * up_e] + bf0,  gf1 = Gs[bl_e][8 + 2 * up_e + 1] + bf1;
        const float gg0 = Gs[bl_e][16 + 2 * up_e] + bg0, gg1 = Gs[bl_e][16 + 2 * up_e + 1] + bg1;
        const float go0 = Gs[bl_e][24 + 2 * up_e] + bo0, go1 = Gs[bl_e][24 + 2 * up_e + 1] + bo1;
        cA = sigmoidf_(gf0) * cA + sigmoidf_(gi0) * tanhf_(gg0);
        cB = sigmoidf_(gf1) * cB + sigmoidf_(gi1) * tanhf_(gg1);
        union { f16 h2v[2]; unsigned u; } pk;
        pk.h2v[0] = (f16)(sigmoidf_(go0) * tanhf_(cA));
        pk.h2v[1] = (f16)(sigmoidf_(go1) * tanhf_(cB));
        unsigned* dst = (unsigned*)(hout + (b0r + bl_e) * 256 + uc0);
        __hip_atomic_store(dst, pk.u, __ATOMIC_RELAXED, __HIP_MEMORY_SCOPE_AGENT);
      }
    }

    if (it <= TT) group_barrier(slots, w, (unsigned)(it + 1), tid);
  }
}

__global__ __launch_bounds__(256, 1) void lstm_persistent(
    const float* __restrict__ x,
    const float* __restrict__ Wih0, const float* __restrict__ Whh0, const float* __restrict__ b0v,
    const float* __restrict__ Wih1, const float* __restrict__ Whh1, const float* __restrict__ b1v,
    f16* h1buf, f16* h2buf, unsigned* F) {
  __shared__ float Gs[64][33];
  const int tid = threadIdx.x, bid = blockIdx.x;
  // barrier group = batch block (bid&3): 32 layer0 + 32 layer1 WGs; w = index in group
  const int g = bid & 3, w = bid >> 2;
  unsigned* slots = F + g * 4096;   // 64 slots x 64 u32 (256B apart)

  if (bid < 128)
    run_layer<0>(x, nullptr, Wih0, Whh0, b0v, h1buf, slots, w, Gs, bid, tid);
  else
    run_layer<1>(nullptr, h1buf, Wih1, Whh1, b1v, h2buf, slots, w, Gs, bid, tid);
}

// final dense (C=10) + softmax on h2[T-1]; one wave per batch row
__global__ __launch_bounds__(64, 1) void dense_softmax_k(const f16* __restrict__ h2,
                                                         const float* __restrict__ Wd,
                                                         const float* __restrict__ bd,
                                                         float* __restrict__ out) {
  const int b = blockIdx.x, lane = threadIdx.x;
  float hv[4];
#pragma unroll
  for (int j = 0; j < 4; ++j) hv[j] = (float)h2[b * 256 + lane + 64 * j];
  float p[10];
#pragma unroll
  for (int c = 0; c < 10; ++c) {
    float s = 0.f;
#pragma unroll
    for (int j = 0; j < 4; ++j) s += hv[j] * Wd[c * 256 + lane + 64 * j];
#pragma unroll
    for (int off = 32; off >= 1; off >>= 1) s += __shfl_xor(s, off, 64);
    p[c] = s;
  }
  if (lane == 0) {
    float mx = -1e30f;
#pragma unroll
    for (int c = 0; c < 10; ++c) { p[c] += bd[c]; mx = fmaxf(mx, p[c]); }
    float den = 0.f;
#pragma unroll
    for (int c = 0; c < 10; ++c) { p[c] = __expf(p[c] - mx); den += p[c]; }
#pragma unroll
    for (int c = 0; c < 10; ++c) out[b * 10 + c] = p[c] / den;
  }
}

extern "C" void kernel_launch(void* const* d_in, const int* in_sizes, int n_in,
                              void* d_out, int out_size, void* d_ws, size_t ws_size,
                              hipStream_t stream) {
  const float* x    = (const float*)d_in[0];
  const float* Wih0 = (const float*)d_in[1];
  const float* Whh0 = (const float*)d_in[2];
  const float* b0v  = (const float*)d_in[3];
  const float* Wih1 = (const float*)d_in[4];
  const float* Whh1 = (const float*)d_in[5];
  const float* b1v  = (const float*)d_in[6];
  const float* Wd   = (const float*)d_in[7];
  const float* bd   = (const float*)d_in[8];

  char* ws = (char*)d_ws;
  // layout: h1buf[2] @0 (256KB) | h2buf[2] @256K (256KB) | slots @512K (64KB)
  f16* h1buf = (f16*)(ws);
  f16* h2buf = (f16*)(ws + 256 * 1024);
  unsigned* F = (unsigned*)(ws + 512 * 1024);

  // zero h1buf[1] + h2buf[0] (initial hidden states, contiguous) and all slots
  hipMemsetAsync(ws + 128 * 1024, 0, 256 * 1024, stream);
  hipMemsetAsync(ws + 512 * 1024, 0, 64 * 1024, stream);

  lstm_persistent<<<256, 256, 0, stream>>>(x, Wih0, Whh0, b0v, Wih1, Whh1, b1v,
                                           h1buf, h2buf, F);
  // h2[T-1] lands in h2buf[0] (T even)
  dense_softmax_k<<<256, 64, 0, stream>>>(h2buf, Wd, bd, (float*)d_out);
}